// Round 1
// baseline (322.964 us; speedup 1.0000x reference)
//
#include <hip/hip_runtime.h>

#define TPB 256

// Problem dims
constexpr int B_ = 4096, A_ = 11, D_ = 256;
constexpr int R_ = B_ * A_;       // 45056 rows
constexpr int K32 = 32;           // L*IN folded input dim

// ws offsets (in floats)
constexpr int WC_O   = 0;          // 4*256   W_in @ W_pos_top
constexpr int XB_O   = 1024;       // 8*256   per-timestep bias (pe etc.)
constexpr int M_O    = 3072;       // 32*256  folded through fc2
constexpr int CB_O   = 11264;      // 256     folded bias through fc2
constexpr int M2_O   = 11520;      // 32*256  folded through fc3
constexpr int B2_O   = 19712;      // 11*256  per-agent bias (ftraj)
constexpr int WN2L_O = 22528;      // 64*64   Wn2 @ W_line
constexpr int MH1_O  = 26624;      // 32*64   M2 @ Wh1
constexpr int BH1_O  = 28672;      // 11*64
constexpr int MH2_O  = 29376;      // 32*64   M2 @ Wh2
constexpr int BH2_O  = 31424;      // 11*64
constexpr int U1_O   = 32768;
constexpr int SZ_RH  = R_ * 64;    // 2883584
constexpr int V1_O   = U1_O + SZ_RH;
constexpr int U2_O   = V1_O + SZ_RH;
constexpr int V2_O   = U2_O + SZ_RH;

// ---------------- precompute: fold weight chains ----------------

__global__ __launch_bounds__(TPB) void k_pre1(const float* __restrict__ Win,
                                              const float* __restrict__ bin,
                                              const float* __restrict__ Wpos,
                                              const float* __restrict__ bpos,
                                              float* __restrict__ ws) {
    int idx = blockIdx.x * TPB + threadIdx.x;   // grid 12 -> 3072
    if (idx < 1024) {                           // Wc[i][j] = sum_d Win[i][d]*Wpos[d][j]
        int i = idx >> 8, j = idx & 255;
        float acc = 0.f;
        for (int d = 0; d < 256; ++d) acc += Win[i*256+d] * Wpos[d*256+j];
        ws[WC_O + idx] = acc;
    } else {                                    // xb[l][j] = b_in@Wpos_top + pe[l]@Wpos_bot + bpos
        int o = idx - 1024;                     // < 2048
        int l = o >> 8, j = o & 255;
        float acc = bpos[j];
        for (int d = 0; d < 256; ++d) acc += bin[d] * Wpos[d*256+j];
        const float c0 = -logf(10000.f) / 256.f;
        for (int i = 0; i < 128; ++i) {
            float freq = expf((float)(2*i) * c0);
            float ang = (float)l * freq;
            acc += sinf(ang) * Wpos[(256 + 2*i)*256 + j];
            acc += cosf(ang) * Wpos[(256 + 2*i + 1)*256 + j];
        }
        ws[XB_O + o] = acc;
    }
}

__global__ __launch_bounds__(TPB) void k_pre2(const float* __restrict__ Wfc2,
                                              const float* __restrict__ bfc2,
                                              float* __restrict__ ws) {
    // grid 33: blocks 0..31 -> M (32x256), block 32 -> cb (256)
    if (blockIdx.x < 32) {
        int idx = blockIdx.x * TPB + threadIdx.x;  // < 8192
        int k = idx >> 8, j = idx & 255;
        int l = k >> 2, i = k & 3;
        float acc = 0.f;
        for (int d = 0; d < 256; ++d)
            acc += ws[WC_O + i*256 + d] * Wfc2[l*65536 + d*256 + j];
        ws[M_O + idx] = acc;
    } else {
        int j = threadIdx.x;
        float acc = bfc2[j];
        for (int l = 0; l < 8; ++l)
            for (int d = 0; d < 256; ++d)
                acc += ws[XB_O + l*256 + d] * Wfc2[l*65536 + d*256 + j];
        ws[CB_O + j] = acc;
    }
}

__global__ __launch_bounds__(TPB) void k_pre3(const float* __restrict__ Wfc3,
                                              const float* __restrict__ bfc3,
                                              const float* __restrict__ Wn2,
                                              const float* __restrict__ Wline,
                                              float* __restrict__ ws) {
    int idx = blockIdx.x * TPB + threadIdx.x;   // grid 59 -> 15104
    if (idx < 8192) {                           // M2 = M @ Wfc3_top
        int k = idx >> 8, j = idx & 255;
        float acc = 0.f;
        for (int d = 0; d < 256; ++d) acc += ws[M_O + k*256 + d] * Wfc3[d*256 + j];
        ws[M2_O + idx] = acc;
    } else if (idx < 11008) {                   // bias2[a] = cb@Wfc3_top + Wfc3[256+a] + bfc3
        int o = idx - 8192;
        int a = o >> 8, j = o & 255;
        float acc = bfc3[j] + Wfc3[(256 + a)*256 + j];
        for (int d = 0; d < 256; ++d) acc += ws[CB_O + d] * Wfc3[d*256 + j];
        ws[B2_O + o] = acc;
    } else if (idx < 15104) {                   // Wn2L = Wn2 @ W_line
        int o = idx - 11008;
        int k = o >> 6, c = o & 63;
        float acc = 0.f;
        for (int d = 0; d < 256; ++d) acc += Wn2[k*256 + d] * Wline[d*64 + c];
        ws[WN2L_O + o] = acc;
    }
}

__global__ __launch_bounds__(TPB) void k_pre4(const float* __restrict__ Wh1,
                                              const float* __restrict__ Wh2,
                                              float* __restrict__ ws) {
    int idx = blockIdx.x * TPB + threadIdx.x;   // grid 22 -> 5632, valid < 5504
    if (idx < 2048) {                           // Mh1 = M2 @ Wh1
        int k = idx >> 6, c = idx & 63;
        float acc = 0.f;
        for (int d = 0; d < 256; ++d) acc += ws[M2_O + k*256 + d] * Wh1[d*64 + c];
        ws[MH1_O + idx] = acc;
    } else if (idx < 2752) {                    // bh1 = bias2 @ Wh1
        int o = idx - 2048;
        int a = o >> 6, c = o & 63;
        float acc = 0.f;
        for (int d = 0; d < 256; ++d) acc += ws[B2_O + a*256 + d] * Wh1[d*64 + c];
        ws[BH1_O + o] = acc;
    } else if (idx < 4800) {                    // Mh2 = M2 @ Wh2
        int o = idx - 2752;
        int k = o >> 6, c = o & 63;
        float acc = 0.f;
        for (int d = 0; d < 256; ++d) acc += ws[M2_O + k*256 + d] * Wh2[d*64 + c];
        ws[MH2_O + o] = acc;
    } else if (idx < 5504) {                    // bh2 = bias2 @ Wh2
        int o = idx - 4800;
        int a = o >> 6, c = o & 63;
        float acc = 0.f;
        for (int d = 0; d < 256; ++d) acc += ws[B2_O + a*256 + d] * Wh2[d*64 + c];
        ws[BH2_O + o] = acc;
    }
}

// ---------------- frontend: ftraj = in @ M2 + bias2[a] -> out[:,0:256] ----------------

__global__ __launch_bounds__(TPB) void k_front(const float* __restrict__ in,
                                               const float* __restrict__ ws,
                                               float* __restrict__ out) {
    __shared__ float M2s[32*256];
    __shared__ float b2s[11*256];
    __shared__ float ins[16*32];
    int tid = threadIdx.x;
    int rowBase = blockIdx.x * 16;
    for (int o = tid; o < 8192; o += TPB) M2s[o] = ws[M2_O + o];
    for (int o = tid; o < 2816; o += TPB) b2s[o] = ws[B2_O + o];
    for (int o = tid; o < 512;  o += TPB) ins[o] = in[rowBase*K32 + o];
    __syncthreads();
    for (int r = 0; r < 16; ++r) {
        int row = rowBase + r;
        int ag = row % 11;
        float acc = b2s[ag*256 + tid];
        #pragma unroll
        for (int k = 0; k < 32; ++k) acc += ins[r*32 + k] * M2s[k*256 + tid];
        out[row*576 + tid] = acc;
    }
}

// ---------------- fused h -> u,v for both NMP stages ----------------

__global__ __launch_bounds__(TPB) void k_uv(const float* __restrict__ in,
                                            const float* __restrict__ We1,
                                            const float* __restrict__ We2,
                                            float* __restrict__ ws) {
    __shared__ float ins[64*33];     // padded stride 33
    __shared__ float hbuf[64*65];    // padded stride 65
    __shared__ float Web[128*64];
    int tid = threadIdx.x;
    int rowBase = blockIdx.x * 64;
    for (int o = tid; o < 2048; o += TPB)
        ins[(o >> 5)*33 + (o & 31)] = in[rowBase*K32 + o];
    for (int o = tid; o < 8192; o += TPB) Web[o] = We1[o];
    __syncthreads();
    const int tcq = tid & 15;
    const int tc = tcq * 4;
    const int tr = (tid >> 4) * 4;

    for (int pass = 0; pass < 2; ++pass) {
        if (pass == 1) {
            for (int o = tid; o < 8192; o += TPB) Web[o] = We2[o];
        }
        const float* gMh = ws + (pass ? MH2_O : MH1_O);
        const float* gBh = ws + (pass ? BH2_O : BH1_O);
        // h = relu(in @ Mh + bh[a])
        float ha[4][4];
        #pragma unroll
        for (int r = 0; r < 4; ++r)
            #pragma unroll
            for (int c = 0; c < 4; ++c) ha[r][c] = 0.f;
        for (int k = 0; k < 32; ++k) {
            float av[4], bv[4];
            #pragma unroll
            for (int r = 0; r < 4; ++r) av[r] = ins[(tr + r)*33 + k];
            #pragma unroll
            for (int c = 0; c < 4; ++c) bv[c] = gMh[k*64 + tc + c];
            #pragma unroll
            for (int r = 0; r < 4; ++r)
                #pragma unroll
                for (int c = 0; c < 4; ++c) ha[r][c] += av[r] * bv[c];
        }
        #pragma unroll
        for (int r = 0; r < 4; ++r) {
            int ag = (rowBase + tr + r) % 11;
            #pragma unroll
            for (int c = 0; c < 4; ++c)
                hbuf[(tr + r)*65 + tc + c] = fmaxf(ha[r][c] + gBh[ag*64 + tc + c], 0.f);
        }
        __syncthreads();
        // u = h @ We_top, v = h @ We_bot
        float ua[4][4], va[4][4];
        #pragma unroll
        for (int r = 0; r < 4; ++r)
            #pragma unroll
            for (int c = 0; c < 4; ++c) { ua[r][c] = 0.f; va[r][c] = 0.f; }
        for (int k = 0; k < 64; ++k) {
            float av[4], bu[4], bw[4];
            #pragma unroll
            for (int r = 0; r < 4; ++r) av[r] = hbuf[(tr + r)*65 + k];
            #pragma unroll
            for (int c = 0; c < 4; ++c) {
                bu[c] = Web[k*64 + tc + c];
                bw[c] = Web[(k + 64)*64 + tc + c];
            }
            #pragma unroll
            for (int r = 0; r < 4; ++r)
                #pragma unroll
                for (int c = 0; c < 4; ++c) {
                    ua[r][c] += av[r] * bu[c];
                    va[r][c] += av[r] * bw[c];
                }
        }
        float* ug = ws + (pass ? U2_O : U1_O);
        float* vg = ws + (pass ? V2_O : V1_O);
        #pragma unroll
        for (int r = 0; r < 4; ++r) {
            int row = rowBase + tr + r;
            *(float4*)(ug + row*64 + tc) = make_float4(ua[r][0], ua[r][1], ua[r][2], ua[r][3]);
            *(float4*)(vg + row*64 + tc) = make_float4(va[r][0], va[r][1], va[r][2], va[r][3]);
        }
        __syncthreads();
    }
}

// ---------------- per-scene: corr/adj + aggregation + tail matmuls ----------------

__global__ __launch_bounds__(TPB) void k_scene(const float* __restrict__ out_ft,
                                               const float* __restrict__ ws,
                                               const float* __restrict__ Wn1,
                                               float* __restrict__ out) {
    __shared__ float ft[11*257];
    __shared__ float dots[121];
    __shared__ float corrv[121];
    __shared__ float u1s[704], v1s[704], u2s[704], v2s[704];
    __shared__ float agg1[704], agg2[704];
    __shared__ float wn2l[4096];
    __shared__ float red[4];
    __shared__ float sthr;
    int tid = threadIdx.x;
    int scene = blockIdx.x;
    int base = scene * 11;

    for (int o = tid; o < 2816; o += TPB)
        ft[(o >> 8)*257 + (o & 255)] = out_ft[(base + (o >> 8))*576 + (o & 255)];
    for (int o = tid; o < 704; o += TPB) {
        u1s[o] = ws[U1_O + scene*704 + o];
        v1s[o] = ws[V1_O + scene*704 + o];
        u2s[o] = ws[U2_O + scene*704 + o];
        v2s[o] = ws[V2_O + scene*704 + o];
    }
    for (int o = tid; o < 4096; o += TPB) wn2l[o] = ws[WN2L_O + o];
    __syncthreads();

    if (tid < 121) {
        int i = tid / 11, j = tid - i*11;
        float acc = 0.f;
        for (int d = 0; d < 256; ++d) acc += ft[i*257 + d] * ft[j*257 + d];
        dots[tid] = acc;
    }
    __syncthreads();
    if (tid < 121) {
        int i = tid / 11, j = tid - i*11;
        corrv[tid] = dots[tid] / sqrtf(dots[i*11 + i] * dots[j*11 + j]);
    }
    __syncthreads();
    // min over all 121 corr values
    float v = (tid < 121) ? corrv[tid] : 3.0e38f;
    for (int off = 32; off > 0; off >>= 1) v = fminf(v, __shfl_down(v, off));
    if ((tid & 63) == 0) red[tid >> 6] = v;
    __syncthreads();
    if (tid == 0) {
        float a = fminf(fminf(red[0], red[1]), fminf(red[2], red[3]));
        sthr = (a < 0.4f) ? 0.4f : ((a > 0.4f && a < 0.6f) ? a + 0.1f : a + 0.03f);
    }
    __syncthreads();
    float thr = sthr;

    // agg1 = mean_j relu(u1_i + v1_j); agg2 = sum_j adj*relu(u2_i+v2_j)/(cnt+1e-6)
    for (int o = tid; o < 704; o += TPB) {
        int i = o >> 6;
        int c = o & 63;
        float u1 = u1s[o], u2 = u2s[o];
        float s1 = 0.f, s2 = 0.f, cnt = 0.f;
        for (int j = 0; j < 11; ++j) {
            int vo = (j << 6) + c;
            s1 += fmaxf(u1 + v1s[vo], 0.f);
            float adj = (corrv[i*11 + j] >= thr) ? 1.f : 0.f;
            s2 += adj * fmaxf(u2 + v2s[vo], 0.f);
            cnt += adj;
        }
        agg1[o] = s1 * (1.f / 11.f);
        agg2[o] = s2 / (cnt + 1e-6f);
    }
    __syncthreads();

    // inter = agg1 @ Wn1 -> out[:,256:512]
    {
        float accs[11];
        #pragma unroll
        for (int i = 0; i < 11; ++i) accs[i] = 0.f;
        for (int k = 0; k < 64; ++k) {
            float w = Wn1[k*256 + tid];
            #pragma unroll
            for (int i = 0; i < 11; ++i) accs[i] += agg1[i*64 + k] * w;
        }
        #pragma unroll
        for (int i = 0; i < 11; ++i) out[(base + i)*576 + 256 + tid] = accs[i];
    }
    // feat = agg2 @ (Wn2 @ W_line) -> out[:,512:576]
    for (int o = tid; o < 704; o += TPB) {
        int i = o >> 6, c = o & 63;
        float acc = 0.f;
        #pragma unroll
        for (int k = 0; k < 64; ++k) acc += agg2[i*64 + k] * wn2l[k*64 + c];
        out[(base + i)*576 + 512 + c] = acc;
    }
}

extern "C" void kernel_launch(void* const* d_in, const int* in_sizes, int n_in,
                              void* d_out, int out_size, void* d_ws, size_t ws_size,
                              hipStream_t stream) {
    (void)in_sizes; (void)n_in; (void)out_size; (void)ws_size;
    const float* in     = (const float*)d_in[0];
    const float* W_in   = (const float*)d_in[1];
    const float* b_in   = (const float*)d_in[2];
    const float* W_pos  = (const float*)d_in[3];
    const float* b_pos  = (const float*)d_in[4];
    const float* W_fc2  = (const float*)d_in[5];
    const float* b_fc2  = (const float*)d_in[6];
    const float* W_fc3  = (const float*)d_in[7];
    const float* b_fc3  = (const float*)d_in[8];
    const float* Wh1    = (const float*)d_in[9];
    const float* We1    = (const float*)d_in[10];
    const float* Wn1    = (const float*)d_in[11];
    const float* Wh2    = (const float*)d_in[12];
    const float* We2    = (const float*)d_in[13];
    const float* Wn2    = (const float*)d_in[14];
    const float* W_line = (const float*)d_in[15];
    float* out = (float*)d_out;
    float* ws  = (float*)d_ws;

    k_pre1<<<12, TPB, 0, stream>>>(W_in, b_in, W_pos, b_pos, ws);
    k_pre2<<<33, TPB, 0, stream>>>(W_fc2, b_fc2, ws);
    k_pre3<<<59, TPB, 0, stream>>>(W_fc3, b_fc3, Wn2, W_line, ws);
    k_pre4<<<22, TPB, 0, stream>>>(Wh1, Wh2, ws);
    k_front<<<R_/16, TPB, 0, stream>>>(in, ws, out);
    k_uv<<<R_/64, TPB, 0, stream>>>(in, We1, We2, ws);
    k_scene<<<B_, TPB, 0, stream>>>(out, ws, Wn1, out);
}